// Round 10
// baseline (155.205 us; speedup 1.0000x reference)
//
#include <hip/hip_runtime.h>
#include <hip/hip_bf16.h>

#define N_SITES 50000
#define N_PERM  12
#define N_NEIGH 8
#define NODE_F  64
#define IN_F    512
#define OUT_F   64
#define N_TILES (N_SITES / 16)   // 3125 exact, one block per tile
#define LN2F    0.69314718055994530942f

#define XCHUNKS (N_SITES * NODE_F / 8)   // 400000 (16B bf16 chunks)
#define WCHUNKS (OUT_F * IN_F / 8)       // 4096
// per-perm staging: 16 DMA slots x (8 rows x 128 B + 16 B pad) = 16640 B
#define SLOT_E  520                       // bf16 elems per slot
#define BUF_E   (16 * SLOT_E)             // 16640 B per buffer

typedef __bf16 bf16x8 __attribute__((ext_vector_type(8)));
typedef float  f32x4  __attribute__((ext_vector_type(4)));

__device__ __forceinline__ unsigned short f32_to_bf16_rne(unsigned int u) {
    u += 0x7FFFu + ((u >> 16) & 1u);
    return (unsigned short)(u >> 16);
}

// Block-uniform dtype probe (R2-R9 proven: live path is fp32 -> 0).
__device__ __forceinline__ int probe_is_bf16(const void* Xorig) {
    int lane = threadIdx.x & 63;
    unsigned short h = ((const unsigned short*)Xorig)[2 * lane];
    int e = (h >> 7) & 0xFF;
    unsigned long long mm = __ballot(e >= 110 && e <= 140);
    return (__popcll(mm) >= 48) ? 1 : 0;
}

__device__ __forceinline__ void pack8(const uint4* src, uint4* dst, int c) {
    uint4 a = src[2 * c], b = src[2 * c + 1];
    uint4 o;
    o.x = (unsigned int)f32_to_bf16_rne(a.x) | ((unsigned int)f32_to_bf16_rne(a.y) << 16);
    o.y = (unsigned int)f32_to_bf16_rne(a.z) | ((unsigned int)f32_to_bf16_rne(a.w) << 16);
    o.z = (unsigned int)f32_to_bf16_rne(b.x) | ((unsigned int)f32_to_bf16_rne(b.y) << 16);
    o.w = (unsigned int)f32_to_bf16_rne(b.z) | ((unsigned int)f32_to_bf16_rne(b.w) << 16);
    dst[c] = o;
}

// Converts X, W (fp32->bf16 or copy) and bias (->f32) into workspace.
__global__ void convert_all(const void* __restrict__ Xv, const void* __restrict__ Wv,
                            const void* __restrict__ Bv, uint4* __restrict__ Xb,
                            uint4* __restrict__ Wb, float* __restrict__ Bf) {
    const int isbf = probe_is_bf16(Xv);
    int c = blockIdx.x * blockDim.x + threadIdx.x;
    if (c < XCHUNKS) {
        if (isbf) Xb[c] = ((const uint4*)Xv)[c];
        else      pack8((const uint4*)Xv, Xb, c);
    } else if (c < XCHUNKS + WCHUNKS) {
        int cw = c - XCHUNKS;
        if (isbf) Wb[cw] = ((const uint4*)Wv)[cw];
        else      pack8((const uint4*)Wv, Wb, cw);
    } else if (c < XCHUNKS + WCHUNKS + OUT_F) {
        int i = c - XCHUNKS - WCHUNKS;
        Bf[i] = isbf ? (float)((const __bf16*)Bv)[i] : ((const float*)Bv)[i];
    }
}

__device__ __forceinline__ float softplus_sh(float x) {
    float t = __expf(-fabsf(x));
    return fmaxf(x, 0.f) + 0.69314718056f * __log2f(1.f + t);
}

__device__ __forceinline__ void async16(const __bf16* g, __bf16* l) {
    __builtin_amdgcn_global_load_lds(
        (const __attribute__((address_space(1))) unsigned int*)g,
        (__attribute__((address_space(3))) unsigned int*)l, 16, 0, 0);
}

// R9 was LDS-read-bound: 1 ds_read_b128 per MFMA (4 waves each re-reading the
// shared A-tile) = ~62 us of LDS-port time. R10: block = 2 waves, one 16-site
// tile; wave w owns out-features 32w..32w+31 (TWO nb-blocks, 32 W B-fragments
// = 128 VGPRs) -> each afr read feeds 2 MFMA -> LDS A-traffic HALVES.
// 128-thr blocks + __launch_bounds__(128,2) -> 256-reg budget; LDS 33.3 KB ->
// 4 blocks/CU = 8 waves/CU (same residency as R9). DMA pattern unchanged:
// full 128 B neighbor rows per 8-lane group (the R9 request-rate win),
// XOR chunk swizzle, 16 B/slot pad, lag-1 double buffer, 1 barrier/perm.
__global__ __launch_bounds__(128, 2)
void lcnn_dma(const void* __restrict__ Xorig, const __bf16* __restrict__ Xb,
              const int* __restrict__ NS, const __bf16* __restrict__ Wb,
              const float* __restrict__ Bf, void* __restrict__ outv)
{
    __shared__ __align__(16) __bf16 Abuf[2][BUF_E];   // 2 x 16640 B

    const int wave = threadIdx.x >> 6;    // 0..1
    const int lane = threadIdx.x & 63;
    const int m    = lane & 15;
    const int quad = lane >> 4;
    const int mk   = m & 7;
    const int mh   = m >> 3;
    const int tile = blockIdx.x;

    // W fragments: [nb][ks], B[k][n] with n = wave*32 + nb*16 + m,
    // k = ks*32 + quad*8 + j  (16 B contiguous)
    bf16x8 Wfrag[2][16];
    #pragma unroll
    for (int nb = 0; nb < 2; ++nb)
        #pragma unroll
        for (int ks = 0; ks < 16; ++ks)
            Wfrag[nb][ks] = *(const bf16x8*)(
                Wb + (size_t)(wave * 32 + nb * 16 + m) * IN_F + ks * 32 + quad * 8);

    const float bias0 = Bf[wave * 32 + m];
    const float bias1 = Bf[wave * 32 + 16 + m];

    // DMA slot t = wave*8 + i: neighbor k = t>>1, site-half = t&1.
    // lane: row-in-slot = lane>>3, source chunk = (lane&7) ^ (lane>>3).
    auto load_idx = [&](int p_, int out[8]) {
        #pragma unroll
        for (int i = 0; i < 8; ++i) {
            int t = wave * 8 + i;
            int s = ((t & 1) << 3) + (lane >> 3);
            int k = t >> 1;
            out[i] = NS[(size_t)(tile * 16 + s) * (N_PERM * N_NEIGH) + p_ * N_NEIGH + k];
        }
    };
    auto stage = [&](int buf_, const int idxv[8]) {
        const int csrc = (lane & 7) ^ (lane >> 3);
        #pragma unroll
        for (int i = 0; i < 8; ++i) {
            int t = wave * 8 + i;
            async16(Xb + (size_t)idxv[i] * NODE_F + csrc * 8, &Abuf[buf_][t * SLOT_E]);
        }
    };

    int idxn[8];
    load_idx(0, idxn);
    stage(0, idxn);
    load_idx(1, idxn);
    __syncthreads();                          // buf0 staged (drains DMA)

    f32x4 sum0 = {0.f, 0.f, 0.f, 0.f}, sum1 = {0.f, 0.f, 0.f, 0.f};
    for (int p = 0; p < N_PERM; ++p) {
        if (p < N_PERM - 1) stage((p + 1) & 1, idxn);   // flies under compute
        if (p < N_PERM - 2) load_idx(p + 2, idxn);      // regs free post-issue

        f32x4 acc0 = {0.f, 0.f, 0.f, 0.f}, acc1 = {0.f, 0.f, 0.f, 0.f};
        const __bf16* bb = &Abuf[p & 1][0];
        #pragma unroll
        for (int ks = 0; ks < 16; ++ks) {
            // row site m -> slot t=(ks>>1)*2+mh, in-slot row mk;
            // chunk j=((ks&1)<<2)|quad stored at position j^mk  (R9-verified)
            int t_r = (ks >> 1) * 2 + mh;
            int j   = ((ks & 1) << 2) | quad;
            bf16x8 afr = *(const bf16x8*)(bb + t_r * SLOT_E + mk * 64 + ((j ^ mk) << 3));
            acc0 = __builtin_amdgcn_mfma_f32_16x16x32_bf16(afr, Wfrag[0][ks], acc0, 0, 0, 0);
            acc1 = __builtin_amdgcn_mfma_f32_16x16x32_bf16(afr, Wfrag[1][ks], acc1, 0, 0, 0);
        }
        #pragma unroll
        for (int r = 0; r < 4; ++r) {
            sum0[r] += softplus_sh(acc0[r] + bias0);
            sum1[r] += softplus_sh(acc1[r] + bias1);
        }
        __syncthreads();                      // next buf ready; this buf free
    }

    // C: row = quad*4 + r (site), out feature = wave*32 + nb*16 + m
    const int isbf = probe_is_bf16(Xorig);
    #pragma unroll
    for (int r = 0; r < 4; ++r) {
        size_t row = (size_t)(tile * 16 + quad * 4 + r) * OUT_F;
        float v0 = sum0[r] - 12.0f * LN2F;
        float v1 = sum1[r] - 12.0f * LN2F;
        if (isbf) {
            ((__bf16*)outv)[row + wave * 32 + m]      = (__bf16)v0;
            ((__bf16*)outv)[row + wave * 32 + 16 + m] = (__bf16)v1;
        } else {
            ((float*)outv)[row + wave * 32 + m]      = v0;
            ((float*)outv)[row + wave * 32 + 16 + m] = v1;
        }
    }
}

// Safety net (workspace too small — never seen): direct fp32 compute.
__global__ void lcnn_fallback(const float* __restrict__ X, const int* __restrict__ NS,
                              const float* __restrict__ W, const float* __restrict__ B,
                              float* __restrict__ out) {
    int t = blockIdx.x * blockDim.x + threadIdx.x;
    if (t >= N_SITES * OUT_F) return;
    int sitei = t >> 6, o = t & 63;
    const int* ns = NS + (size_t)sitei * 96;
    float s = 0.f;
    for (int p = 0; p < N_PERM; ++p) {
        float x = B[o];
        for (int n = 0; n < N_NEIGH; ++n) {
            const float* xr = X + (size_t)ns[p * 8 + n] * NODE_F;
            const float* wr = W + (size_t)o * IN_F + n * NODE_F;
            for (int f = 0; f < NODE_F; ++f) x += xr[f] * wr[f];
        }
        s += softplus_sh(x);
    }
    out[t] = s - 12.0f * LN2F;
}

extern "C" void kernel_launch(void* const* d_in, const int* in_sizes, int n_in,
                              void* d_out, int out_size, void* d_ws, size_t ws_size,
                              hipStream_t stream) {
    const void* X  = d_in[0];                // (50000, 64)
    const int*  NS = (const int*)d_in[1];    // (50000, 12, 8) int32
    const void* W  = d_in[2];                // (64, 512)
    const void* B  = d_in[3];                // (64,)

    char* ws = (char*)d_ws;
    __bf16* Xb = (__bf16*)ws;                                     // 6.4 MB
    __bf16* Wb = (__bf16*)(ws + (size_t)XCHUNKS * 16);            // 64 KB
    float*  Bf = (float*)(ws + (size_t)(XCHUNKS + WCHUNKS) * 16); // 256 B
    const bool conv = ws_size >= (size_t)(XCHUNKS + WCHUNKS) * 16 + OUT_F * 4;

    if (conv) {
        int nch = XCHUNKS + WCHUNKS + OUT_F;
        hipLaunchKernelGGL(convert_all, dim3((nch + 255) / 256), dim3(256), 0, stream,
                           X, W, B, (uint4*)Xb, (uint4*)Wb, Bf);
        hipLaunchKernelGGL(lcnn_dma, dim3(N_TILES), dim3(128), 0, stream,
                           X, Xb, NS, Wb, Bf, d_out);
    } else {
        hipLaunchKernelGGL(lcnn_fallback,
                           dim3((N_SITES * OUT_F + 255) / 256), dim3(256), 0, stream,
                           (const float*)X, NS, (const float*)W, (const float*)B,
                           (float*)d_out);
    }
}